// Round 8
// baseline (138.034 us; speedup 1.0000x reference)
//
#include <hip/hip_runtime.h>
#include <hip/hip_bf16.h>
#include <stdint.h>
#include <stddef.h>

// ---------- types ----------
typedef __attribute__((ext_vector_type(8))) short bfrag8;   // 8 bf16 in 4 VGPRs
typedef __attribute__((ext_vector_type(4))) float facc4;    // MFMA accumulator

#define SCALING 0.17677669529663687f   // 32^-0.5

__device__ __forceinline__ unsigned short f2bf(float f) {
  union { float f; unsigned u; } v; v.f = f;
  unsigned r = v.u + 0x7fffu + ((v.u >> 16) & 1u);   // RNE
  return (unsigned short)(r >> 16);
}

// ---------------------------------------------------------------------------
// Kernel 1: fp32 -> bf16 convert for query, W_in, W_out
// ---------------------------------------------------------------------------
__global__ __launch_bounds__(256)
void convert_bf16(const float* __restrict__ q, const float* __restrict__ wi,
                  const float* __restrict__ wo,
                  unsigned short* __restrict__ qb, unsigned short* __restrict__ wib,
                  unsigned short* __restrict__ wob) {
  int t = blockIdx.x * 256 + threadIdx.x;
  const float4* src; unsigned short* dst; int idx;
  if (t < 524288)            { src = (const float4*)q;  dst = qb;  idx = t; }
  else if (t < 524288+196608){ src = (const float4*)wi; dst = wib; idx = t - 524288; }
  else                       { src = (const float4*)wo; dst = wob; idx = t - 720896; }
  float4 v = src[idx];
  ushort4 o;
  o.x = f2bf(v.x); o.y = f2bf(v.y); o.z = f2bf(v.z); o.w = f2bf(v.w);
  *(ushort4*)(dst + (size_t)idx * 4) = o;
}

// ---------------------------------------------------------------------------
// Kernel 2/5: GEMM  C[M x N] = A[M x 512] * B[N x 512]^T
// MODE 0: qkv epilogue; MODE 1: out epilogue
// ---------------------------------------------------------------------------
template<int MODE>
__global__ __launch_bounds__(256, 2)
void gemm_bt(const unsigned short* __restrict__ A, const unsigned short* __restrict__ Bw,
             const float* __restrict__ bias,
             unsigned short* __restrict__ oQ, unsigned short* __restrict__ oK,
             unsigned short* __restrict__ oV, float* __restrict__ oF) {
  constexpr int K = 512;
  __shared__ __align__(16) unsigned short lA[2][64 * 32];
  __shared__ __align__(16) unsigned short lB[2][128 * 32];
  const int t = threadIdx.x;
  const int w = t >> 6, l = t & 63;
  const int lr = l & 15, lg = l >> 4;
  const int mBase = blockIdx.x * 64;
  const int nBase = blockIdx.y * 128;
  const int wr = w >> 1, wc = w & 1;

  facc4 acc[2][4];
#pragma unroll
  for (int i = 0; i < 2; i++)
#pragma unroll
    for (int j = 0; j < 4; j++) acc[i][j] = (facc4){0.f, 0.f, 0.f, 0.f};

  const int arow = t & 63, aslot = t >> 6;
  const unsigned short* aSrc = A + (size_t)(mBase + arow) * K + aslot * 8;
  const int bcol0 = t & 127, bslot0 = t >> 7;
  const int bcol1 = (256 + t) & 127, bslot1 = (256 + t) >> 7;
  const unsigned short* bSrc0 = Bw + (size_t)(nBase + bcol0) * K + bslot0 * 8;
  const unsigned short* bSrc1 = Bw + (size_t)(nBase + bcol1) * K + bslot1 * 8;

  auto stage = [&](int ks, int buf) {
    const int kB = ks * 32;
    *(int4*)(&lA[buf][(size_t)t * 8])         = *(const int4*)(aSrc + kB);
    *(int4*)(&lB[buf][(size_t)t * 8])         = *(const int4*)(bSrc0 + kB);
    *(int4*)(&lB[buf][(size_t)(256 + t) * 8]) = *(const int4*)(bSrc1 + kB);
  };

  stage(0, 0);
  __syncthreads();
#pragma unroll 1
  for (int ks = 0; ks < 16; ks++) {
    const int buf = ks & 1;
    if (ks < 15) stage(ks + 1, buf ^ 1);
    bfrag8 af[2], bfr[4];
#pragma unroll
    for (int qi = 0; qi < 2; qi++)
      af[qi] = *(const bfrag8*)(&lA[buf][(lg * 64 + wr * 32 + qi * 16 + lr) * 8]);
#pragma unroll
    for (int nj = 0; nj < 4; nj++)
      bfr[nj] = *(const bfrag8*)(&lB[buf][(lg * 128 + wc * 64 + nj * 16 + lr) * 8]);
#pragma unroll
    for (int qi = 0; qi < 2; qi++)
#pragma unroll
      for (int nj = 0; nj < 4; nj++)
        acc[qi][nj] = __builtin_amdgcn_mfma_f32_16x16x32_bf16(af[qi], bfr[nj], acc[qi][nj], 0, 0, 0);
    __syncthreads();
  }

#pragma unroll
  for (int qi = 0; qi < 2; qi++)
#pragma unroll
    for (int nj = 0; nj < 4; nj++) {
      int m0 = mBase + wr * 32 + qi * 16 + lg * 4;
      int o = nBase + wc * 64 + nj * 16 + lr;
      float bv = bias[o];
#pragma unroll
      for (int r = 0; r < 4; r++) {
        float v = acc[qi][nj][r] + bv;
        int mm = m0 + r;
        if (MODE == 0) {
          int n = mm >> 2, g = mm & 3;
          int chunk = o >> 9, cc = o & 511, h = cc >> 5, d = cc & 31;
          size_t oidx = ((size_t)(g * 16 + h) * 1024 + n) * 32 + d;
          if (chunk == 0)      oQ[oidx] = f2bf(v * SCALING);
          else if (chunk == 1) oK[oidx] = f2bf(v);
          else                 oV[oidx] = f2bf(v);
        } else {
          oF[(size_t)mm * 512 + o] = v;
        }
      }
    }
}

// ---------------------------------------------------------------------------
// Kernel 3: V [gh][n][32] -> Vt [gh][32][n]   (grid 64 x 4, 256-row tiles)
// ---------------------------------------------------------------------------
__global__ __launch_bounds__(256)
void transpose_v(const unsigned short* __restrict__ V, unsigned short* __restrict__ Vt) {
  __shared__ unsigned short tile[32][264];
  const int gh = blockIdx.x, n0 = blockIdx.y * 256;
  const int t = threadIdx.x;
  const unsigned short* src = V + ((size_t)gh * 1024 + n0) * 32;
#pragma unroll
  for (int c = 0; c < 4; c++) {
    int j = c * 256 + t; int row = j >> 2, d0 = (j & 3) * 8;
    bfrag8 v = *(const bfrag8*)(src + (size_t)row * 32 + d0);
#pragma unroll
    for (int i = 0; i < 8; i++) tile[d0 + i][row] = (unsigned short)v[i];
  }
  __syncthreads();
  unsigned short* dst = Vt + (size_t)gh * 32 * 1024 + n0;
#pragma unroll
  for (int c = 0; c < 4; c++) {
    int j = c * 256 + t; int d = j >> 5, n8 = (j & 31) * 8;
    *(bfrag8*)(dst + (size_t)d * 1024 + n8) = *(const bfrag8*)(&tile[d][n8]);
  }
}

// ---------------------------------------------------------------------------
// Kernel 4: fused flash attention — round-8: FULL-ROW BIAS STREAMING.
//
// r3/r5/r6/r7 all land at ~100-105 us attn: throughput-capped at ~2.5 TB/s
// with queue-inflated latency (which is why pipelining/instr-count/stagger
// were all null). Invariant across them: bias read as 64-256 B chunks at
// 4 KB row stride => ~256 B per DRAM page activation => ~40% efficiency.
// THIS round changes the DRAM-visible pattern only: K is processed in 4
// phases of 256 cols; each wave stages its 16 q-rows x 256 cols (16 KB)
// into a per-wave LDS buffer via 16x global_load_lds where each wave
// instruction reads ONE ROW's 1 KB CONTIGUOUSLY (the 6.3 TB/s ubench
// pattern). Compute reads bias from LDS (rows padded to 260 f32 -> 2-way
// bank aliasing only, which is free). No barriers; vmcnt(0) per phase.
// LDS: 4 x 16.25 KB bias + 8 KB P = 73 KB -> 2 blocks/CU (8 waves/CU;
// fine if BW-bound: issue floor ~16 us << 41 us BW floor).
// ---------------------------------------------------------------------------
__global__ __launch_bounds__(256)
void attn_kernel(const unsigned short* __restrict__ Qs, const unsigned short* __restrict__ Ks,
                 const unsigned short* __restrict__ Vt, const float* __restrict__ biasG,
                 unsigned short* __restrict__ Out) {
  __shared__ __align__(16) float biasL[4][16 * 260];        // 65 KB: per-wave [16][260]
  __shared__ __align__(16) unsigned short Pl[4][16 * 64];   // 8 KB, per-wave P tile
  const int gh = blockIdx.x, q0 = blockIdx.y * 64;
  const int t = threadIdx.x, w = t >> 6, l = t & 63;
  const int lr = l & 15, lg = l >> 4;

  const unsigned short* Qg = Qs + (size_t)gh * 1024 * 32;
  const unsigned short* Kg = Ks + (size_t)gh * 1024 * 32;
  const unsigned short* Vg = Vt + (size_t)gh * 32 * 1024;
  // this wave's 16 bias rows: q = q0 + w*16 + c
  const float* Bw = biasG + (size_t)gh * 1048576 + (size_t)(q0 + w * 16) * 1024;

  bfrag8 qf = *(const bfrag8*)(Qg + (size_t)(q0 + w * 16 + lr) * 32 + lg * 8);

  facc4 accO[2];
  accO[0] = (facc4){0.f, 0.f, 0.f, 0.f};
  accO[1] = (facc4){0.f, 0.f, 0.f, 0.f};
  float mrun[4], lrun[4];
#pragma unroll
  for (int r = 0; r < 4; r++) { mrun[r] = -3.0e38f; lrun[r] = 0.f; }

  unsigned short* Pw = Pl[w];
  float* bL = &biasL[w][0];

  // stage row c (1 KB contiguous: 64 lanes x 16 B) of phase g into LDS
  auto stageRow = [&](int g, int c) {
    __builtin_amdgcn_global_load_lds(
        (const __attribute__((address_space(1))) unsigned int*)(Bw + (size_t)c * 1024 + g * 256 + l * 4),
        (__attribute__((address_space(3))) unsigned int*)(bL + c * 260),
        16, 0, 0);
  };

#pragma unroll
  for (int c = 0; c < 16; c++) stageRow(0, c);

#pragma unroll 1
  for (int g = 0; g < 4; g++) {
    // wait for this phase's 16 row-chunks (issued at end of previous phase)
    asm volatile("s_waitcnt vmcnt(0)" ::: "memory");
#pragma unroll 1
    for (int ktl = 0; ktl < 4; ktl++) {
      const int kb = g * 256 + ktl * 64;
      // bias from LDS -> MFMA C operand (row lg*4+r, col ktl*64+j*16+lr)
      facc4 sc[4];
#pragma unroll
      for (int j = 0; j < 4; j++)
#pragma unroll
        for (int r = 0; r < 4; r++)
          sc[j][r] = bL[(lg * 4 + r) * 260 + ktl * 64 + j * 16 + lr];
      // QK^T accumulating onto the bias
#pragma unroll
      for (int j = 0; j < 4; j++) {
        bfrag8 kf = *(const bfrag8*)(Kg + (size_t)(kb + j * 16 + lr) * 32 + lg * 8);
        sc[j] = __builtin_amdgcn_mfma_f32_16x16x32_bf16(qf, kf, sc[j], 0, 0, 0);
      }
      // row max over this tile (16-lane column groups)
      float tm[4];
#pragma unroll
      for (int r = 0; r < 4; r++) tm[r] = -3.0e38f;
#pragma unroll
      for (int j = 0; j < 4; j++)
#pragma unroll
        for (int r = 0; r < 4; r++) tm[r] = fmaxf(tm[r], sc[j][r]);
#pragma unroll
      for (int mk = 1; mk < 16; mk <<= 1)
#pragma unroll
        for (int r = 0; r < 4; r++) tm[r] = fmaxf(tm[r], __shfl_xor(tm[r], mk, 64));
      // online softmax update
      float scale[4];
#pragma unroll
      for (int r = 0; r < 4; r++) {
        float mn = fmaxf(mrun[r], tm[r]);
        scale[r] = __expf(mrun[r] - mn);
        mrun[r] = mn;
      }
      float rs[4] = {0.f, 0.f, 0.f, 0.f};
#pragma unroll
      for (int j = 0; j < 4; j++)
#pragma unroll
        for (int r = 0; r < 4; r++) {
          float p = __expf(sc[j][r] - mrun[r]);
          rs[r] += p;
          int row = lg * 4 + r, col = j * 16 + lr;
          int byte = (row * 128 + col * 2) ^ ((row & 7) << 4);
          *(unsigned short*)((char*)Pw + byte) = f2bf(p);
        }
#pragma unroll
      for (int mk = 1; mk < 16; mk <<= 1)
#pragma unroll
        for (int r = 0; r < 4; r++) rs[r] += __shfl_xor(rs[r], mk, 64);
#pragma unroll
      for (int r = 0; r < 4; r++) lrun[r] = lrun[r] * scale[r] + rs[r];
#pragma unroll
      for (int h = 0; h < 2; h++)
#pragma unroll
        for (int r = 0; r < 4; r++) accO[h][r] *= scale[r];
      // PV (P A-frags from own-wave LDS; V B-frags 16B-contiguous from Vt)
#pragma unroll
      for (int ksb = 0; ksb < 2; ksb++) {
        int byte = (lr * 128 + (ksb * 32 + lg * 8) * 2) ^ ((lr & 7) << 4);
        bfrag8 pf = *(const bfrag8*)((char*)Pw + byte);
#pragma unroll
        for (int h = 0; h < 2; h++) {
          bfrag8 vf = *(const bfrag8*)(Vg + (size_t)(h * 16 + lr) * 1024 + kb + ksb * 32 + lg * 8);
          accO[h] = __builtin_amdgcn_mfma_f32_16x16x32_bf16(pf, vf, accO[h], 0, 0, 0);
        }
      }
    }
    // issue next phase's staging (overlaps with the other resident block;
    // waited by the vmcnt(0) at the top of phase g+1)
    if (g < 3) {
#pragma unroll
      for (int c = 0; c < 16; c++) stageRow(g + 1, c);
    }
  }

  // epilogue: O / l  -> attn_out bf16 [4096, 512]
  const int g = gh >> 4, hh = gh & 15;
#pragma unroll
  for (int h = 0; h < 2; h++)
#pragma unroll
    for (int r = 0; r < 4; r++) {
      int q = q0 + w * 16 + lg * 4 + r;
      float v = accO[h][r] / lrun[r];
      int e = hh * 32 + h * 16 + lr;
      Out[(size_t)(q * 4 + g) * 512 + e] = f2bf(v);
    }
}

// ---------------------------------------------------------------------------
extern "C" void kernel_launch(void* const* d_in, const int* in_sizes, int n_in,
                              void* d_out, int out_size, void* d_ws, size_t ws_size,
                              hipStream_t stream) {
  (void)in_sizes; (void)n_in; (void)out_size; (void)ws_size;
  const float* query = (const float*)d_in[0];
  const float* abias = (const float*)d_in[1];
  const float* W_in  = (const float*)d_in[2];
  const float* b_in  = (const float*)d_in[3];
  const float* W_out = (const float*)d_in[4];
  const float* b_out = (const float*)d_in[5];
  float* out = (float*)d_out;
  char* ws = (char*)d_ws;
  unsigned short* qbf  = (unsigned short*)(ws);             // 4 MB
  unsigned short* wibf = (unsigned short*)(ws + 4194304);   // 1.5 MB
  unsigned short* wobf = (unsigned short*)(ws + 5767168);   // 0.5 MB
  unsigned short* Qs   = (unsigned short*)(ws + 6291456);   // 4 MB  [gh][n][d]
  unsigned short* Ks   = (unsigned short*)(ws + 10485760);  // 4 MB  [gh][n][d]
  unsigned short* Vv   = (unsigned short*)(ws + 14680064);  // 4 MB  [gh][n][d]
  unsigned short* Vt   = (unsigned short*)(ws + 18874368);  // 4 MB  [gh][d][n]
  unsigned short* attO = (unsigned short*)(ws + 23068672);  // 4 MB  [m][e]

  convert_bf16<<<3072, 256, 0, stream>>>(query, W_in, W_out, qbf, wibf, wobf);
  gemm_bt<0><<<dim3(64, 12), 256, 0, stream>>>(qbf, wibf, b_in, Qs, Ks, Vv, nullptr);
  transpose_v<<<dim3(64, 4), 256, 0, stream>>>(Vv, Vt);
  attn_kernel<<<dim3(64, 16), 256, 0, stream>>>(Qs, Ks, Vt, abias, attO);
  gemm_bt<1><<<dim3(64, 4), 256, 0, stream>>>(attO, wobf, b_out, nullptr, nullptr, nullptr, out);
}

// Round 9
// 135.414 us; speedup vs baseline: 1.0193x; 1.0193x over previous
//
#include <hip/hip_runtime.h>
#include <hip/hip_bf16.h>
#include <stdint.h>
#include <stddef.h>

// ---------- types ----------
typedef __attribute__((ext_vector_type(8))) short bfrag8;   // 8 bf16 in 4 VGPRs
typedef __attribute__((ext_vector_type(4))) float facc4;    // MFMA accumulator

#define SCALING 0.17677669529663687f   // 32^-0.5

__device__ __forceinline__ unsigned short f2bf(float f) {
  union { float f; unsigned u; } v; v.f = f;
  unsigned r = v.u + 0x7fffu + ((v.u >> 16) & 1u);   // RNE
  return (unsigned short)(r >> 16);
}

// ---------------------------------------------------------------------------
// Kernel 1: fp32 -> bf16 convert for query, W_in, W_out
// ---------------------------------------------------------------------------
__global__ __launch_bounds__(256)
void convert_bf16(const float* __restrict__ q, const float* __restrict__ wi,
                  const float* __restrict__ wo,
                  unsigned short* __restrict__ qb, unsigned short* __restrict__ wib,
                  unsigned short* __restrict__ wob) {
  int t = blockIdx.x * 256 + threadIdx.x;
  const float4* src; unsigned short* dst; int idx;
  if (t < 524288)            { src = (const float4*)q;  dst = qb;  idx = t; }
  else if (t < 524288+196608){ src = (const float4*)wi; dst = wib; idx = t - 524288; }
  else                       { src = (const float4*)wo; dst = wob; idx = t - 720896; }
  float4 v = src[idx];
  ushort4 o;
  o.x = f2bf(v.x); o.y = f2bf(v.y); o.z = f2bf(v.z); o.w = f2bf(v.w);
  *(ushort4*)(dst + (size_t)idx * 4) = o;
}

// ---------------------------------------------------------------------------
// Kernel 2/5: GEMM  C[M x N] = A[M x 512] * B[N x 512]^T
// MODE 0: qkv epilogue; MODE 1: out epilogue
// ---------------------------------------------------------------------------
template<int MODE>
__global__ __launch_bounds__(256, 2)
void gemm_bt(const unsigned short* __restrict__ A, const unsigned short* __restrict__ Bw,
             const float* __restrict__ bias,
             unsigned short* __restrict__ oQ, unsigned short* __restrict__ oK,
             unsigned short* __restrict__ oV, float* __restrict__ oF) {
  constexpr int K = 512;
  __shared__ __align__(16) unsigned short lA[2][64 * 32];
  __shared__ __align__(16) unsigned short lB[2][128 * 32];
  const int t = threadIdx.x;
  const int w = t >> 6, l = t & 63;
  const int lr = l & 15, lg = l >> 4;
  const int mBase = blockIdx.x * 64;
  const int nBase = blockIdx.y * 128;
  const int wr = w >> 1, wc = w & 1;

  facc4 acc[2][4];
#pragma unroll
  for (int i = 0; i < 2; i++)
#pragma unroll
    for (int j = 0; j < 4; j++) acc[i][j] = (facc4){0.f, 0.f, 0.f, 0.f};

  const int arow = t & 63, aslot = t >> 6;
  const unsigned short* aSrc = A + (size_t)(mBase + arow) * K + aslot * 8;
  const int bcol0 = t & 127, bslot0 = t >> 7;
  const int bcol1 = (256 + t) & 127, bslot1 = (256 + t) >> 7;
  const unsigned short* bSrc0 = Bw + (size_t)(nBase + bcol0) * K + bslot0 * 8;
  const unsigned short* bSrc1 = Bw + (size_t)(nBase + bcol1) * K + bslot1 * 8;

  auto stage = [&](int ks, int buf) {
    const int kB = ks * 32;
    *(int4*)(&lA[buf][(size_t)t * 8])         = *(const int4*)(aSrc + kB);
    *(int4*)(&lB[buf][(size_t)t * 8])         = *(const int4*)(bSrc0 + kB);
    *(int4*)(&lB[buf][(size_t)(256 + t) * 8]) = *(const int4*)(bSrc1 + kB);
  };

  stage(0, 0);
  __syncthreads();
#pragma unroll 1
  for (int ks = 0; ks < 16; ks++) {
    const int buf = ks & 1;
    if (ks < 15) stage(ks + 1, buf ^ 1);
    bfrag8 af[2], bfr[4];
#pragma unroll
    for (int qi = 0; qi < 2; qi++)
      af[qi] = *(const bfrag8*)(&lA[buf][(lg * 64 + wr * 32 + qi * 16 + lr) * 8]);
#pragma unroll
    for (int nj = 0; nj < 4; nj++)
      bfr[nj] = *(const bfrag8*)(&lB[buf][(lg * 128 + wc * 64 + nj * 16 + lr) * 8]);
#pragma unroll
    for (int qi = 0; qi < 2; qi++)
#pragma unroll
      for (int nj = 0; nj < 4; nj++)
        acc[qi][nj] = __builtin_amdgcn_mfma_f32_16x16x32_bf16(af[qi], bfr[nj], acc[qi][nj], 0, 0, 0);
    __syncthreads();
  }

#pragma unroll
  for (int qi = 0; qi < 2; qi++)
#pragma unroll
    for (int nj = 0; nj < 4; nj++) {
      int m0 = mBase + wr * 32 + qi * 16 + lg * 4;
      int o = nBase + wc * 64 + nj * 16 + lr;
      float bv = bias[o];
#pragma unroll
      for (int r = 0; r < 4; r++) {
        float v = acc[qi][nj][r] + bv;
        int mm = m0 + r;
        if (MODE == 0) {
          int n = mm >> 2, g = mm & 3;
          int chunk = o >> 9, cc = o & 511, h = cc >> 5, d = cc & 31;
          size_t oidx = ((size_t)(g * 16 + h) * 1024 + n) * 32 + d;
          if (chunk == 0)      oQ[oidx] = f2bf(v * SCALING);
          else if (chunk == 1) oK[oidx] = f2bf(v);
          else                 oV[oidx] = f2bf(v);
        } else {
          oF[(size_t)mm * 512 + o] = v;
        }
      }
    }
}

// ---------------------------------------------------------------------------
// Kernel 3: V [gh][n][32] -> Vt [gh][32][n]   (grid 64 x 4, 256-row tiles)
// ---------------------------------------------------------------------------
__global__ __launch_bounds__(256)
void transpose_v(const unsigned short* __restrict__ V, unsigned short* __restrict__ Vt) {
  __shared__ unsigned short tile[32][264];
  const int gh = blockIdx.x, n0 = blockIdx.y * 256;
  const int t = threadIdx.x;
  const unsigned short* src = V + ((size_t)gh * 1024 + n0) * 32;
#pragma unroll
  for (int c = 0; c < 4; c++) {
    int j = c * 256 + t; int row = j >> 2, d0 = (j & 3) * 8;
    bfrag8 v = *(const bfrag8*)(src + (size_t)row * 32 + d0);
#pragma unroll
    for (int i = 0; i < 8; i++) tile[d0 + i][row] = (unsigned short)v[i];
  }
  __syncthreads();
  unsigned short* dst = Vt + (size_t)gh * 32 * 1024 + n0;
#pragma unroll
  for (int c = 0; c < 4; c++) {
    int j = c * 256 + t; int d = j >> 5, n8 = (j & 31) * 8;
    *(bfrag8*)(dst + (size_t)d * 1024 + n8) = *(const bfrag8*)(&tile[d][n8]);
  }
}

// ---------------------------------------------------------------------------
// Kernel 4: fused flash attention — round-9: 512B-RUN BIAS STREAM, 2-DEEP
// COUNTED-VMCNT PIPELINE (clean test of the DRAM-run-length theory r8 fumbled).
//
// vs r3 (best, 122.5): ONLY the bias delivery changes. Big-iter = 128 cols;
// each wave stages its OWN 16 rows x 512B into biasT[2][64][128] via 8x
// global_load_lds (1KB = 2 rows per instr, 4 consecutive 128B lines per row
// vs r3's 2) with 2-big-iter lookahead. Counted s_waitcnt vmcnt(8) at loop
// top (vmcnt(0) on the last) -> stages stay in flight ~2 big-iters; no
// barriers anywhere (per-wave rows, per-wave P). Bank swizzle folded into
// the GLOBAL source address (chunk ^ ((rowInWave>>2)&3)); read side XORs the
// same key -> 2-way LDS aliasing (free). LDS 72KB -> 2 blocks/CU, 8 waves.
// If this nulls too, run-length/page theory is dead (pipeline is provably
// covered this time) and the attn structure is at its request-path cap.
// ---------------------------------------------------------------------------
__global__ __launch_bounds__(256)
void attn_kernel(const unsigned short* __restrict__ Qs, const unsigned short* __restrict__ Ks,
                 const unsigned short* __restrict__ Vt, const float* __restrict__ biasG,
                 unsigned short* __restrict__ Out) {
  __shared__ __align__(16) float biasT[2][64][128];         // 64 KB dbuf
  __shared__ __align__(16) unsigned short Pl[4][16 * 64];   // 8 KB per-wave P
  const int gh = blockIdx.x, q0 = blockIdx.y * 64;
  const int t = threadIdx.x, w = t >> 6, l = t & 63;
  const int lr = l & 15, lg = l >> 4;

  const unsigned short* Qg = Qs + (size_t)gh * 32768;
  const unsigned short* Kg = Ks + (size_t)gh * 32768;
  const unsigned short* Vg = Vt + (size_t)gh * 32768;
  // wave's 16 bias rows: q = q0 + w*16 + rl
  const float* Bw = biasG + (size_t)gh * 1048576 + (size_t)(q0 + w * 16) * 1024;

  // staging lane geometry: instr i stages rows {2i, 2i+1}; lane l ->
  // row-in-pair (l>>5), 64B chunk (l>>2)&7, 16B sub l&3. Source chunk is
  // pre-XORed with key_i = (i>>1)&3 so the linear LDS write realizes the
  // swizzle; reads XOR the same key (= lg for row lg*4+r).
  const int rpair  = l >> 5;
  const int chunkB = ((l >> 2) & 7) << 6;
  const int subB   = (l & 3) << 4;

  bfrag8 qf = *(const bfrag8*)(Qg + (size_t)(q0 + w * 16 + lr) * 32 + lg * 8);

  facc4 accO[2];
  accO[0] = (facc4){0.f, 0.f, 0.f, 0.f};
  accO[1] = (facc4){0.f, 0.f, 0.f, 0.f};
  float mrun[4], lrun[4];
#pragma unroll
  for (int r = 0; r < 4; r++) { mrun[r] = -3.0e38f; lrun[r] = 0.f; }

  unsigned short* Pw = Pl[w];

  auto stageBias = [&](int bt, int buf) {
#pragma unroll
    for (int i = 0; i < 8; i++) {
      const int key = ((i >> 1) & 3) << 6;
      const char* src = (const char*)(Bw + (size_t)(i * 2 + rpair) * 1024 + bt * 128)
                        + ((chunkB ^ key) + subB);
      __builtin_amdgcn_global_load_lds(
          (const __attribute__((address_space(1))) unsigned int*)src,
          (__attribute__((address_space(3))) unsigned int*)(&biasT[buf][w * 16 + i * 2][0]),
          16, 0, 0);
    }
  };

  stageBias(0, 0);
  stageBias(1, 1);

#pragma unroll 1
  for (int bt = 0; bt < 8; bt++) {
    const int buf = bt & 1;
    if (bt == 7) asm volatile("s_waitcnt vmcnt(0)" ::: "memory");
    else         asm volatile("s_waitcnt vmcnt(8)" ::: "memory");
    __builtin_amdgcn_sched_barrier(0);

#pragma unroll
    for (int s64 = 0; s64 < 2; s64++) {
      const int kb = bt * 128 + s64 * 64;
      // bias from LDS -> MFMA C operand (swizzled scalar reads, 2-way free)
      facc4 sc[4];
#pragma unroll
      for (int j = 0; j < 4; j++)
#pragma unroll
        for (int r = 0; r < 4; r++)
          sc[j][r] = *(const float*)((const char*)&biasT[buf][w * 16 + lg * 4 + r][0]
                       + ((((s64 * 4 + j) ^ lg) << 6) + (lr << 2)));
      // QK^T accumulating onto the bias
#pragma unroll
      for (int j = 0; j < 4; j++) {
        bfrag8 kf = *(const bfrag8*)(Kg + (size_t)(kb + j * 16 + lr) * 32 + lg * 8);
        sc[j] = __builtin_amdgcn_mfma_f32_16x16x32_bf16(qf, kf, sc[j], 0, 0, 0);
      }
      // row max over this tile (16-lane column groups)
      float tm[4];
#pragma unroll
      for (int r = 0; r < 4; r++) tm[r] = -3.0e38f;
#pragma unroll
      for (int j = 0; j < 4; j++)
#pragma unroll
        for (int r = 0; r < 4; r++) tm[r] = fmaxf(tm[r], sc[j][r]);
#pragma unroll
      for (int mk = 1; mk < 16; mk <<= 1)
#pragma unroll
        for (int r = 0; r < 4; r++) tm[r] = fmaxf(tm[r], __shfl_xor(tm[r], mk, 64));
      // online softmax update
      float scale[4];
#pragma unroll
      for (int r = 0; r < 4; r++) {
        float mn = fmaxf(mrun[r], tm[r]);
        scale[r] = __expf(mrun[r] - mn);
        mrun[r] = mn;
      }
      float rs[4] = {0.f, 0.f, 0.f, 0.f};
#pragma unroll
      for (int j = 0; j < 4; j++)
#pragma unroll
        for (int r = 0; r < 4; r++) {
          float p = __expf(sc[j][r] - mrun[r]);
          rs[r] += p;
          int row = lg * 4 + r, col = j * 16 + lr;
          int byte = (row * 128 + col * 2) ^ ((row & 7) << 4);
          *(unsigned short*)((char*)Pw + byte) = f2bf(p);
        }
#pragma unroll
      for (int mk = 1; mk < 16; mk <<= 1)
#pragma unroll
        for (int r = 0; r < 4; r++) rs[r] += __shfl_xor(rs[r], mk, 64);
#pragma unroll
      for (int r = 0; r < 4; r++) lrun[r] = lrun[r] * scale[r] + rs[r];
#pragma unroll
      for (int h = 0; h < 2; h++)
#pragma unroll
        for (int r = 0; r < 4; r++) accO[h][r] *= scale[r];
      // PV (P A-frags from own-wave LDS; V B-frags 16B-contiguous from Vt)
#pragma unroll
      for (int ksb = 0; ksb < 2; ksb++) {
        int byte = (lr * 128 + (ksb * 32 + lg * 8) * 2) ^ ((lr & 7) << 4);
        bfrag8 pf = *(const bfrag8*)((char*)Pw + byte);
#pragma unroll
        for (int h = 0; h < 2; h++) {
          bfrag8 vf = *(const bfrag8*)(Vg + (size_t)(h * 16 + lr) * 1024 + kb + ksb * 32 + lg * 8);
          accO[h] = __builtin_amdgcn_mfma_f32_16x16x32_bf16(pf, vf, accO[h], 0, 0, 0);
        }
      }
    }

    __builtin_amdgcn_sched_barrier(0);
    if (bt < 6) stageBias(bt + 2, buf);
    __builtin_amdgcn_sched_barrier(0);
  }

  // epilogue: O / l  -> attn_out bf16 [4096, 512]
  const int g = gh >> 4, hh = gh & 15;
#pragma unroll
  for (int h = 0; h < 2; h++)
#pragma unroll
    for (int r = 0; r < 4; r++) {
      int q = q0 + w * 16 + lg * 4 + r;
      float v = accO[h][r] / lrun[r];
      int e = hh * 32 + h * 16 + lr;
      Out[(size_t)(q * 4 + g) * 512 + e] = f2bf(v);
    }
}

// ---------------------------------------------------------------------------
extern "C" void kernel_launch(void* const* d_in, const int* in_sizes, int n_in,
                              void* d_out, int out_size, void* d_ws, size_t ws_size,
                              hipStream_t stream) {
  (void)in_sizes; (void)n_in; (void)out_size; (void)ws_size;
  const float* query = (const float*)d_in[0];
  const float* abias = (const float*)d_in[1];
  const float* W_in  = (const float*)d_in[2];
  const float* b_in  = (const float*)d_in[3];
  const float* W_out = (const float*)d_in[4];
  const float* b_out = (const float*)d_in[5];
  float* out = (float*)d_out;
  char* ws = (char*)d_ws;
  unsigned short* qbf  = (unsigned short*)(ws);             // 4 MB
  unsigned short* wibf = (unsigned short*)(ws + 4194304);   // 1.5 MB
  unsigned short* wobf = (unsigned short*)(ws + 5767168);   // 0.5 MB
  unsigned short* Qs   = (unsigned short*)(ws + 6291456);   // 4 MB  [gh][n][d]
  unsigned short* Ks   = (unsigned short*)(ws + 10485760);  // 4 MB  [gh][n][d]
  unsigned short* Vv   = (unsigned short*)(ws + 14680064);  // 4 MB  [gh][n][d]
  unsigned short* Vt   = (unsigned short*)(ws + 18874368);  // 4 MB  [gh][d][n]
  unsigned short* attO = (unsigned short*)(ws + 23068672);  // 4 MB  [m][e]

  convert_bf16<<<3072, 256, 0, stream>>>(query, W_in, W_out, qbf, wibf, wobf);
  gemm_bt<0><<<dim3(64, 12), 256, 0, stream>>>(qbf, wibf, b_in, Qs, Ks, Vv, nullptr);
  transpose_v<<<dim3(64, 4), 256, 0, stream>>>(Vv, Vt);
  attn_kernel<<<dim3(64, 16), 256, 0, stream>>>(Qs, Ks, Vt, abias, attO);
  gemm_bt<1><<<dim3(64, 4), 256, 0, stream>>>(attO, wobf, b_out, nullptr, nullptr, nullptr, out);
}